// Round 6
// baseline (362.148 us; speedup 1.0000x reference)
//
#include <hip/hip_runtime.h>

#define D_   64
#define CH   32      // chunk width: 2 phases of 32 columns
#define NBT_ 12800   // B*T = 32*400
#define B_   32

// Broadcast lane l's value of v to all lanes (SGPR result).
__device__ __forceinline__ float rl(float v, int l) {
    return __uint_as_float(__builtin_amdgcn_readlane(__float_as_uint(v), l));
}

// Two-phase LEFT-LOOKING Cholesky, one wave per 64x64 matrix, lane = row.
//
// R5 post-mortem: CH=16 (48 KB LDS/block) capped residency at 3 blocks/CU
// -> 20% occupancy -> readlane/LDS latency exposed (true VALU busy ~32%;
// the 64% VALUBusy metric uses the gfx94x 4-cyc formula, gfx950 issues in
// 2). CH=32 drops LDS to 32 KB/block -> 5 blocks/CU = 5 waves/SIMD, and
// collapses 6 apply-pairs into 1. Spill-free working set: cur[32] +
// streamed tmp + ~15 misc ~= 55 VGPRs.
//
//   phase A: load cols 0..31, factor right-looking (fwd-sub+logdet fused),
//            retire panel to LDS (column-major, per-lane private)
//   phase B: load cols 32..63, rank-32 apply streaming the retired panel
//            from LDS one column at a time, then factor.
//
// LDS is per-lane private (lane j re-reads only lds[..][..][j]; broadcasts
// go through readlane of the streamed register) -> no __syncthreads.
// Column-major: lane stride 1 -> conflict-free.
__global__ __launch_bounds__(256) void chol_ll(const float* __restrict__ x,
                                               const float* __restrict__ mu,
                                               const float* __restrict__ sigma,
                                               float* __restrict__ partial) {
    __shared__ float lds[4][CH][D_];   // 4 waves x 32 cols x 64 rows = 32 KB
    const int lane = threadIdx.x & 63;
    const int wv   = threadIdx.x >> 6;
    const int bt   = blockIdx.x * 4 + wv;

    const float* base = sigma + (size_t)bt * (D_ * D_) + (size_t)lane * D_;
    float d = x[bt * D_ + lane] - mu[bt * D_ + lane];
    float q = 0.f, lg = 0.f;

    float cur[CH];

    // ================= phase A: columns 0..31 =================
    {
        const float4* p = (const float4*)base;
        #pragma unroll
        for (int r = 0; r < CH / 4; ++r) {
            float4 v = p[r];
            cur[4 * r + 0] = v.x; cur[4 * r + 1] = v.y;
            cur[4 * r + 2] = v.z; cur[4 * r + 3] = v.w;
        }
        #pragma unroll
        for (int kk = 0; kk < CH; ++kk) {
            float s   = rl(cur[kk], kk) + 1e-6f;     // diag + EPS
            float inv = __builtin_amdgcn_rsqf(s);    // 1/L[kk][kk]
            lg += __builtin_amdgcn_logf(s);          // log2(s); scaled at end
            cur[kk] *= inv;                          // L[lane][kk], lanes >= kk
            float zk = rl(d, kk) * inv;              // forward substitution
            q += zk * zk;
            d = __builtin_fmaf(-cur[kk], zk, d);
            #pragma unroll
            for (int c = kk + 1; c < CH; ++c)
                cur[c] = __builtin_fmaf(-cur[kk], rl(cur[kk], c), cur[c]);
        }
        // retire panel (upper-triangle lanes hold garbage; never re-read)
        #pragma unroll
        for (int k = 0; k < CH; ++k) lds[wv][k][lane] = cur[k];
    }

    // ================= phase B: columns 32..63 =================
    {
        const float4* p = (const float4*)(base + CH);
        #pragma unroll
        for (int r = 0; r < CH / 4; ++r) {
            float4 v = p[r];
            cur[4 * r + 0] = v.x; cur[4 * r + 1] = v.y;
            cur[4 * r + 2] = v.z; cur[4 * r + 3] = v.w;
        }
        // rank-32 apply: stream retired columns back one at a time
        float tn = lds[wv][0][lane];
        #pragma unroll
        for (int k = 0; k < CH; ++k) {
            float tk = tn;
            if (k + 1 < CH) tn = lds[wv][k + 1][lane];   // prefetch next column
            #pragma unroll
            for (int c = 0; c < CH; ++c)
                cur[c] = __builtin_fmaf(-tk, rl(tk, CH + c), cur[c]);
        }
        // factor trailing 32x32 block
        #pragma unroll
        for (int kk = 0; kk < CH; ++kk) {
            const int gk = CH + kk;
            float s   = rl(cur[kk], gk) + 1e-6f;
            float inv = __builtin_amdgcn_rsqf(s);
            lg += __builtin_amdgcn_logf(s);
            cur[kk] *= inv;
            float zk = rl(d, gk) * inv;
            q += zk * zk;
            d = __builtin_fmaf(-cur[kk], zk, d);
            #pragma unroll
            for (int c = kk + 1; c < CH; ++c)
                cur[c] = __builtin_fmaf(-cur[kk], rl(cur[kk], CH + c), cur[c]);
        }
    }

    if (lane == 0) {
        float log_det = 0.34657359027997264f * lg;   // 0.5 * ln2 * sum(log2 s)
        float lp = -0.5f * q - log_det - 58.81206612509905f;  // -0.5*D*ln(2pi)
        partial[bt] = lp;
    }
}

__global__ __launch_bounds__(1024) void reduce_ll(const float* __restrict__ partial,
                                                  float* __restrict__ out) {
    float s = 0.f;
    for (int i = threadIdx.x; i < NBT_; i += 1024) s += partial[i];
    #pragma unroll
    for (int off = 32; off > 0; off >>= 1) s += __shfl_down(s, off, 64);
    __shared__ float ws[16];
    const int lane = threadIdx.x & 63, w = threadIdx.x >> 6;
    if (lane == 0) ws[w] = s;
    __syncthreads();
    if (threadIdx.x == 0) {
        float t = 0.f;
        #pragma unroll
        for (int i = 0; i < 16; ++i) t += ws[i];
        out[0] = -t / (float)B_;   // out = -mean_b sum_t log_prob
    }
}

extern "C" void kernel_launch(void* const* d_in, const int* in_sizes, int n_in,
                              void* d_out, int out_size, void* d_ws, size_t ws_size,
                              hipStream_t stream) {
    const float* x     = (const float*)d_in[0];
    const float* mu    = (const float*)d_in[1];
    const float* sigma = (const float*)d_in[2];
    float* partial = (float*)d_ws;   // NBT_ floats = 51.2 KB scratch
    chol_ll<<<NBT_ / 4, 256, 0, stream>>>(x, mu, sigma, partial);
    reduce_ll<<<1, 1024, 0, stream>>>(partial, (float*)d_out);
}